// Round 1
// baseline (341.500 us; speedup 1.0000x reference)
//
#include <hip/hip_runtime.h>
#include <hip/hip_bf16.h>

// Problem constants
#define BB 16
#define TT 2048
#define CC 128
#define HH 128

typedef __bf16 bf16x8 __attribute__((ext_vector_type(8)));
typedef float  f32x4  __attribute__((ext_vector_type(4)));

// load 8 consecutive fp32 and convert to a bf16x8 MFMA fragment
static __device__ __forceinline__ bf16x8 load_cvt8(const float* __restrict__ p) {
    float4 a = *(const float4*)p;
    float4 b = *(const float4*)(p + 4);
    bf16x8 r;
    r[0] = (__bf16)a.x; r[1] = (__bf16)a.y; r[2] = (__bf16)a.z; r[3] = (__bf16)a.w;
    r[4] = (__bf16)b.x; r[5] = (__bf16)b.y; r[6] = (__bf16)b.z; r[7] = (__bf16)b.w;
    return r;
}

// ---------------------------------------------------------------------------
// Projection kernel: Q = x Wq^T * (C^-0.5 * log2e)  -> ws[0]      [b][t][h]
//                    K = x Wk^T                      -> ws[1]      [b][t][h]
//                    V^T = (x Wv^T)^T                -> ws[2]      [b][h][t]
// grid = (512, 3), block = 256 (4 waves). Each block: 64 rows x 128 cols.
// ---------------------------------------------------------------------------
__global__ __launch_bounds__(256) void proj_kernel(
    const float* __restrict__ x, const float* __restrict__ Wq,
    const float* __restrict__ Wk, const float* __restrict__ Wv,
    __bf16* __restrict__ ws)
{
    const int lane = threadIdx.x & 63;
    const int wave = threadIdx.x >> 6;
    const int quad = lane >> 4;
    const int l16  = lane & 15;
    const int which = blockIdx.y;          // 0=Q, 1=K, 2=V
    const int m0 = blockIdx.x * 64;        // flattened row tile (b*T + t)

    __bf16* out = ws + (size_t)which * ((size_t)BB * TT * HH);

    if (which < 2) {
        const float* W = (which == 0) ? Wq : Wk;
        // Q carries softmax scale (1/sqrt(C)) * log2(e) folded in
        const float sc = (which == 0) ? (0.08838834764831845f * 1.4426950408889634f) : 1.0f;
        const int row = m0 + wave * 16 + l16;
        bf16x8 af[4];
        #pragma unroll
        for (int ks = 0; ks < 4; ++ks)
            af[ks] = load_cvt8(x + (size_t)row * CC + ks * 32 + quad * 8);
        #pragma unroll
        for (int nt = 0; nt < 8; ++nt) {
            f32x4 acc = {0.f, 0.f, 0.f, 0.f};
            #pragma unroll
            for (int ks = 0; ks < 4; ++ks) {
                bf16x8 wf = load_cvt8(W + (size_t)(nt * 16 + l16) * CC + ks * 32 + quad * 8);
                acc = __builtin_amdgcn_mfma_f32_16x16x32_bf16(af[ks], wf, acc, 0, 0, 0);
            }
            #pragma unroll
            for (int r = 0; r < 4; ++r) {
                int ro = m0 + wave * 16 + quad * 4 + r;
                out[(size_t)ro * HH + nt * 16 + l16] = (__bf16)(acc[r] * sc);
            }
        }
    } else {
        // V^T: swap operand roles -> A = Wv (m = h), B = x (n = t).
        // C-layout: col(lane&15) = t, row(quad*4+reg) = h  -> coalesced [h][t] stores.
        const int b  = m0 / TT;
        const int t0 = m0 % TT;
        bf16x8 af[2][4];
        #pragma unroll
        for (int msub = 0; msub < 2; ++msub) {
            const int hrow = wave * 32 + msub * 16 + l16;
            #pragma unroll
            for (int ks = 0; ks < 4; ++ks)
                af[msub][ks] = load_cvt8(Wv + (size_t)hrow * CC + ks * 32 + quad * 8);
        }
        #pragma unroll
        for (int nt = 0; nt < 4; ++nt) {
            bf16x8 xf[4];
            #pragma unroll
            for (int ks = 0; ks < 4; ++ks)
                xf[ks] = load_cvt8(x + (size_t)(m0 + nt * 16 + l16) * CC + ks * 32 + quad * 8);
            #pragma unroll
            for (int msub = 0; msub < 2; ++msub) {
                f32x4 acc = {0.f, 0.f, 0.f, 0.f};
                #pragma unroll
                for (int ks = 0; ks < 4; ++ks)
                    acc = __builtin_amdgcn_mfma_f32_16x16x32_bf16(af[msub][ks], xf[ks], acc, 0, 0, 0);
                #pragma unroll
                for (int r = 0; r < 4; ++r) {
                    int h = wave * 32 + msub * 16 + quad * 4 + r;
                    int t = t0 + nt * 16 + l16;
                    out[((size_t)b * HH + h) * TT + t] = (__bf16)acc[r];
                }
            }
        }
    }
}

// ---------------------------------------------------------------------------
// Flash attention kernel. grid = (32, 16), block = 256 (4 waves).
// Block handles 64 q rows of one batch; wave owns 16 rows.
// Online softmax in exp2 domain (scale*log2e folded into Q).
// P C-layout -> A-layout via wave-private LDS (no __syncthreads needed).
// ---------------------------------------------------------------------------
#define S_LDS 76   // LDS row stride (bf16 elems): conflict-free writes, 8B-aligned reads

__global__ __launch_bounds__(256) void attn_kernel(
    const __bf16* __restrict__ ws, float* __restrict__ outp)
{
    __shared__ __bf16 lds_p[4 * 16 * S_LDS];

    const int lane = threadIdx.x & 63;
    const int wave = threadIdx.x >> 6;
    const int quad = lane >> 4;
    const int l16  = lane & 15;

    const int b = blockIdx.y;
    const int qtile = gridDim.x - 1 - blockIdx.x;   // heavy (late) q-tiles first
    const int q0  = qtile * 64;
    const int qr0 = q0 + wave * 16;

    const __bf16* Q  = ws;
    const __bf16* K  = ws + (size_t)BB * TT * HH;
    const __bf16* Vt = ws + (size_t)2 * BB * TT * HH;

    // Q A-fragments for this wave's 16 rows (stay in registers for all tiles)
    bf16x8 qf[4];
    #pragma unroll
    for (int ks = 0; ks < 4; ++ks)
        qf[ks] = *(const bf16x8*)(Q + (size_t)(b * TT + qr0 + l16) * HH + ks * 32 + quad * 8);

    float m_r[4], l_r[4];
    f32x4 o[8];
    #pragma unroll
    for (int r = 0; r < 4; ++r) { m_r[r] = -1e30f; l_r[r] = 0.f; }
    #pragma unroll
    for (int h8 = 0; h8 < 8; ++h8) o[h8] = (f32x4){0.f, 0.f, 0.f, 0.f};

    __bf16* myP = lds_p + wave * 16 * S_LDS;   // wave-private staging

    const int ntiles = qtile + 1;
    for (int kt = 0; kt < ntiles; ++kt) {
        const int k0 = kt * 64;

        // ---- S = Q K^T (log2-domain scores), 16 rows x 64 keys -------------
        f32x4 s[4];
        #pragma unroll
        for (int nsub = 0; nsub < 4; ++nsub) {
            f32x4 acc = {0.f, 0.f, 0.f, 0.f};
            #pragma unroll
            for (int ks = 0; ks < 4; ++ks) {
                bf16x8 kf = *(const bf16x8*)(K + (size_t)(b * TT + k0 + nsub * 16 + l16) * HH + ks * 32 + quad * 8);
                acc = __builtin_amdgcn_mfma_f32_16x16x32_bf16(qf[ks], kf, acc, 0, 0, 0);
            }
            s[nsub] = acc;
        }

        // ---- causal mask (only diagonal-adjacent tiles need it) ------------
        if (k0 + 63 > qr0) {
            #pragma unroll
            for (int nsub = 0; nsub < 4; ++nsub) {
                int key = k0 + nsub * 16 + l16;
                #pragma unroll
                for (int r = 0; r < 4; ++r) {
                    int row = qr0 + quad * 4 + r;
                    if (key > row) s[nsub][r] = -1e30f;
                }
            }
        }

        // ---- online softmax ------------------------------------------------
        float mnew[4], alpha[4], rs[4];
        #pragma unroll
        for (int r = 0; r < 4; ++r) {
            float rm = fmaxf(fmaxf(s[0][r], s[1][r]), fmaxf(s[2][r], s[3][r]));
            #pragma unroll
            for (int j = 1; j <= 8; j <<= 1)
                rm = fmaxf(rm, __shfl_xor(rm, j, 64));
            float mn = fmaxf(m_r[r], rm);
            alpha[r] = __builtin_amdgcn_exp2f(m_r[r] - mn);
            mnew[r] = mn;
        }
        #pragma unroll
        for (int r = 0; r < 4; ++r) rs[r] = 0.f;
        #pragma unroll
        for (int nsub = 0; nsub < 4; ++nsub) {
            #pragma unroll
            for (int r = 0; r < 4; ++r) {
                float p = __builtin_amdgcn_exp2f(s[nsub][r] - mnew[r]);
                s[nsub][r] = p;
                rs[r] += p;
            }
        }
        #pragma unroll
        for (int r = 0; r < 4; ++r) {
            #pragma unroll
            for (int j = 1; j <= 8; j <<= 1)
                rs[r] += __shfl_xor(rs[r], j, 64);
            l_r[r] = l_r[r] * alpha[r] + rs[r];
            m_r[r] = mnew[r];
        }
        #pragma unroll
        for (int h8 = 0; h8 < 8; ++h8)
            #pragma unroll
            for (int r = 0; r < 4; ++r)
                o[h8][r] *= alpha[r];

        // ---- P: C-layout -> A-layout via wave-private LDS ------------------
        #pragma unroll
        for (int nsub = 0; nsub < 4; ++nsub)
            #pragma unroll
            for (int r = 0; r < 4; ++r)
                myP[(quad * 4 + r) * S_LDS + nsub * 16 + l16] = (__bf16)s[nsub][r];

        asm volatile("s_waitcnt lgkmcnt(0)" ::: "memory");

        bf16x8 pf[2];
        #pragma unroll
        for (int ks2 = 0; ks2 < 2; ++ks2) {
            union { bf16x8 v; uint2 h[2]; } u;
            const char* base = (const char*)myP + (size_t)l16 * (S_LDS * 2) + ks2 * 64 + quad * 16;
            u.h[0] = *(const uint2*)base;
            u.h[1] = *(const uint2*)(base + 8);
            pf[ks2] = u.v;
        }

        // ---- O += P V (V^T layout gives contiguous B-fragments) ------------
        #pragma unroll
        for (int h8 = 0; h8 < 8; ++h8) {
            const __bf16* vb = Vt + (size_t)(b * HH + h8 * 16 + l16) * TT + k0 + quad * 8;
            bf16x8 vf0 = *(const bf16x8*)vb;
            bf16x8 vf1 = *(const bf16x8*)(vb + 32);
            o[h8] = __builtin_amdgcn_mfma_f32_16x16x32_bf16(pf[0], vf0, o[h8], 0, 0, 0);
            o[h8] = __builtin_amdgcn_mfma_f32_16x16x32_bf16(pf[1], vf1, o[h8], 0, 0, 0);
        }
    }

    // ---- epilogue: normalize and store fp32 --------------------------------
    float inv[4];
    #pragma unroll
    for (int r = 0; r < 4; ++r) inv[r] = 1.0f / l_r[r];
    #pragma unroll
    for (int h8 = 0; h8 < 8; ++h8)
        #pragma unroll
        for (int r = 0; r < 4; ++r)
            outp[(size_t)(b * TT + qr0 + quad * 4 + r) * HH + h8 * 16 + l16] = o[h8][r] * inv[r];
}

extern "C" void kernel_launch(void* const* d_in, const int* in_sizes, int n_in,
                              void* d_out, int out_size, void* d_ws, size_t ws_size,
                              hipStream_t stream)
{
    const float* x  = (const float*)d_in[0];
    const float* Wq = (const float*)d_in[1];
    const float* Wk = (const float*)d_in[2];
    const float* Wv = (const float*)d_in[3];
    __bf16* ws = (__bf16*)d_ws;          // needs 3 * 16*2048*128 * 2 B = 25.2 MB
    float* out = (float*)d_out;

    dim3 pgrid(512, 3);
    proj_kernel<<<pgrid, 256, 0, stream>>>(x, Wq, Wk, Wv, ws);

    dim3 agrid(TT / 64, BB);
    attn_kernel<<<agrid, 256, 0, stream>>>(ws, out);
}